// Round 4
// baseline (597.463 us; speedup 1.0000x reference)
//
#include <hip/hip_runtime.h>
#include <math.h>

#define B_ 2
#define T_ 2048
#define D_ 1024
#define H_ 16
#define HD_ 64
#define M_ 16384
#define SCALE_F 4096.0f
#define LDP 3072
#define ST 72            // LDS row stride (shorts) for attn tiles

using short8 = __attribute__((ext_vector_type(8))) short;
using bf16x8 = __attribute__((ext_vector_type(8))) __bf16;
using f32x4  = __attribute__((ext_vector_type(4))) float;

__device__ __forceinline__ unsigned short f2bf(float x){
  unsigned u = __builtin_bit_cast(unsigned, x);
  u += 0x7fffu + ((u >> 16) & 1u);          // RNE
  return (unsigned short)(u >> 16);
}
__device__ __forceinline__ float bf2f(unsigned short h){
  unsigned u = ((unsigned)h) << 16;
  return __builtin_bit_cast(float, u);
}

__device__ __forceinline__ float wsum(float v){
  #pragma unroll
  for (int off = 32; off; off >>= 1) v += __shfl_xor(v, off);
  return v;
}

__device__ __forceinline__ void ld_g2l16(const unsigned short* g, unsigned short* l){
  __builtin_amdgcn_global_load_lds(
      (const __attribute__((address_space(1))) void*)g,
      (__attribute__((address_space(3))) void*)l, 16, 0, 0);
}

// ---------------------------------------------------------------------------
// One-shot fp32 -> bf16 hi/lo conversion for all GEMM operands.
// ---------------------------------------------------------------------------
__global__ __launch_bounds__(256)
void cvt_all(const float* __restrict__ x, const float* __restrict__ Wq,
             const float* __restrict__ Wk, const float* __restrict__ Wv,
             const float* __restrict__ Wo,
             unsigned short* __restrict__ Xhi, unsigned short* __restrict__ Xlo,
             unsigned short* __restrict__ Whi, unsigned short* __restrict__ Wlo,
             unsigned short* __restrict__ Wohi)
{
  const int i = blockIdx.x*256 + threadIdx.x;
  const float* src; unsigned short* hi; unsigned short* lo = nullptr; int rel;
  if      (i < 1048576){ src = x;  hi = Xhi;            lo = Xlo;            rel = i; }
  else if (i < 1310720){ src = Wq; hi = Whi;            lo = Wlo;            rel = i - 1048576; }
  else if (i < 1572864){ src = Wk; hi = Whi + 1048576;  lo = Wlo + 1048576;  rel = i - 1310720; }
  else if (i < 1835008){ src = Wv; hi = Whi + 2097152;                       rel = i - 1572864; }
  else                 { src = Wo; hi = Wohi;                                rel = i - 1835008; }
  float4 v = *(const float4*)(src + (size_t)rel*4);
  unsigned short h0=f2bf(v.x), h1=f2bf(v.y), h2=f2bf(v.z), h3=f2bf(v.w);
  uint2 hh; hh.x = (unsigned)h0 | ((unsigned)h1 << 16);
            hh.y = (unsigned)h2 | ((unsigned)h3 << 16);
  *(uint2*)(hi + (size_t)rel*4) = hh;
  if (lo){
    uint2 ll;
    ll.x = (unsigned)f2bf(v.x-bf2f(h0)) | ((unsigned)f2bf(v.y-bf2f(h1)) << 16);
    ll.y = (unsigned)f2bf(v.z-bf2f(h2)) | ((unsigned)f2bf(v.w-bf2f(h3)) << 16);
    *(uint2*)(lo + (size_t)rel*4) = ll;
  }
}

// ---------------------------------------------------------------------------
// m97-structure GEMM: C[m, n0+n] = sum_k A[m,k]*B[n,k] + bias[n]
// XCD-chunked block swizzle (T1). COMP: hi staged via global_load_lds; lo
// operands are per-lane-private fragments loaded straight global->VGPR
// (no LDS round-trip; same bf16 values -> bit-identical accumulation).
// ---------------------------------------------------------------------------
template<bool COMP>
__global__ __launch_bounds__(256)
void gemm_lds(const unsigned short* __restrict__ Ahi_g, const unsigned short* __restrict__ Alo_g,
              const unsigned short* __restrict__ Bhi_g, const unsigned short* __restrict__ Blo_g,
              const float* __restrict__ bias0, const float* __restrict__ bias1,
              const float* __restrict__ bias2,
              float* __restrict__ C, int ldc)
{
  __shared__ __align__(16) unsigned short Ah[128*32];
  __shared__ __align__(16) unsigned short Bh[128*32];

  const int tid = threadIdx.x, lane = tid & 63, wv = tid >> 6;
  const int wm = wv >> 1, wn = wv & 1;
  const int mi = lane & 15, quad = lane >> 4;

  // bijective XCD swizzle (nwg % 8 == 0 for both instantiations)
  int bid = blockIdx.y*gridDim.x + blockIdx.x;
  const int cpx = (gridDim.x*gridDim.y) >> 3;
  bid = (bid & 7)*cpx + (bid >> 3);
  const int n0 = (bid % gridDim.x) * 128;
  const int m0 = (bid / gridDim.x) * 128;

  const int seg = n0 >> 10;
  const float* bias = (seg == 0) ? bias0 : (seg == 1) ? bias1 : bias2;
  const int nw = n0 & 1023;
  const bool comp = COMP && (seg < 2);

  f32x4 acc[4][4];
  #pragma unroll
  for (int a = 0; a < 4; ++a)
    #pragma unroll
    for (int b = 0; b < 4; ++b)
      acc[a][b] = (f32x4){0.f, 0.f, 0.f, 0.f};

  for (int k0 = 0; k0 < 1024; k0 += 32){
    __syncthreads();
    #pragma unroll
    for (int t = 0; t < 2; ++t){
      int j = wv*128 + t*64 + lane;
      int row = j >> 2, c16 = j & 3;
      size_t ga = (size_t)(m0 + row)*1024 + k0 + c16*8;
      size_t gb = (size_t)(n0 + row)*1024 + k0 + c16*8;
      ld_g2l16(Ahi_g + ga, Ah + j*8);
      ld_g2l16(Bhi_g + gb, Bh + j*8);
    }
    // lo fragments straight to VGPR; drained by the same barrier below
    short8 alr[4], blr[4];
    if (comp){
      #pragma unroll
      for (int a = 0; a < 4; ++a){
        int r = m0 + wm*64 + a*16 + mi;
        alr[a] = *(const short8*)(Alo_g + (size_t)r*1024 + k0 + quad*8);
      }
      #pragma unroll
      for (int b = 0; b < 4; ++b){
        int r = n0 + wn*64 + b*16 + mi;
        blr[b] = *(const short8*)(Blo_g + (size_t)r*1024 + k0 + quad*8);
      }
    }
    __syncthreads();

    bf16x8 ah[4];
    #pragma unroll
    for (int a = 0; a < 4; ++a){
      int r = wm*64 + a*16 + mi;
      ah[a] = __builtin_bit_cast(bf16x8, *(const short8*)(Ah + r*32 + quad*8));
    }
    #pragma unroll
    for (int b = 0; b < 4; ++b){
      int r = wn*64 + b*16 + mi;
      bf16x8 bh = __builtin_bit_cast(bf16x8, *(const short8*)(Bh + r*32 + quad*8));
      if (comp){
        bf16x8 bl = __builtin_bit_cast(bf16x8, blr[b]);
        #pragma unroll
        for (int a = 0; a < 4; ++a){
          bf16x8 al = __builtin_bit_cast(bf16x8, alr[a]);
          acc[a][b] = __builtin_amdgcn_mfma_f32_16x16x32_bf16(al,    bh, acc[a][b], 0, 0, 0);
          acc[a][b] = __builtin_amdgcn_mfma_f32_16x16x32_bf16(ah[a], bl, acc[a][b], 0, 0, 0);
          acc[a][b] = __builtin_amdgcn_mfma_f32_16x16x32_bf16(ah[a], bh, acc[a][b], 0, 0, 0);
        }
      } else {
        #pragma unroll
        for (int a = 0; a < 4; ++a)
          acc[a][b] = __builtin_amdgcn_mfma_f32_16x16x32_bf16(ah[a], bh, acc[a][b], 0, 0, 0);
      }
    }
  }
  #pragma unroll
  for (int a = 0; a < 4; ++a)
    #pragma unroll
    for (int b = 0; b < 4; ++b)
      #pragma unroll
      for (int r = 0; r < 4; ++r){
        int row  = m0 + wm*64 + a*16 + quad*4 + r;
        int coll = wn*64 + b*16 + mi;
        C[(size_t)row*ldc + n0 + coll] = acc[a][b][r] + bias[nw + coll];
      }
}

// ---------------------------------------------------------------------------
// Normalize q,k rows of P; emit head-major bf16: Qhi/Qlo/Khi/Klo/Vbf
// ---------------------------------------------------------------------------
__global__ __launch_bounds__(256)
void norm_split(const float* __restrict__ P,
                unsigned short* __restrict__ Qhi, unsigned short* __restrict__ Qlo,
                unsigned short* __restrict__ Khi, unsigned short* __restrict__ Klo,
                unsigned short* __restrict__ Vbf)
{
  const int row = blockIdx.x, tid = threadIdx.x;
  const int bb = row >> 11, t = row & 2047;
  const int lane = tid & 63, wv = tid >> 6;
  const size_t base = (size_t)row * LDP;
  float4 q4 = *(const float4*)(P + base + tid*4);
  float4 k4 = *(const float4*)(P + base + 1024 + tid*4);
  float4 v4 = *(const float4*)(P + base + 2048 + tid*4);
  float sq = wsum(q4.x*q4.x + q4.y*q4.y + q4.z*q4.z + q4.w*q4.w);
  float sk = wsum(k4.x*k4.x + k4.y*k4.y + k4.z*k4.z + k4.w*k4.w);
  __shared__ float rq[4], rk[4];
  if (lane == 0){ rq[wv] = sq; rk[wv] = sk; }
  __syncthreads();
  float cq = 1.f / fmaxf(sqrtf(rq[0]+rq[1]+rq[2]+rq[3]), 1e-12f);
  float ck = 1.f / fmaxf(sqrtf(rk[0]+rk[1]+rk[2]+rk[3]), 1e-12f);
  float qf[4] = {q4.x*cq, q4.y*cq, q4.z*cq, q4.w*cq};
  float kf[4] = {k4.x*ck, k4.y*ck, k4.z*ck, k4.w*ck};

  const int h = tid >> 4, d0 = (tid & 15)*4;
  const size_t ob = ((size_t)(bb*H_ + h)*T_ + t)*64 + d0;

  uint2 qh, ql, kh, kl, vv;
  unsigned short t0,t1,t2,t3;
  t0=f2bf(qf[0]); t1=f2bf(qf[1]); t2=f2bf(qf[2]); t3=f2bf(qf[3]);
  qh.x = t0 | ((unsigned)t1<<16); qh.y = t2 | ((unsigned)t3<<16);
  ql.x = f2bf(qf[0]-bf2f(t0)) | ((unsigned)f2bf(qf[1]-bf2f(t1))<<16);
  ql.y = f2bf(qf[2]-bf2f(t2)) | ((unsigned)f2bf(qf[3]-bf2f(t3))<<16);
  t0=f2bf(kf[0]); t1=f2bf(kf[1]); t2=f2bf(kf[2]); t3=f2bf(kf[3]);
  kh.x = t0 | ((unsigned)t1<<16); kh.y = t2 | ((unsigned)t3<<16);
  kl.x = f2bf(kf[0]-bf2f(t0)) | ((unsigned)f2bf(kf[1]-bf2f(t1))<<16);
  kl.y = f2bf(kf[2]-bf2f(t2)) | ((unsigned)f2bf(kf[3]-bf2f(t3))<<16);
  vv.x = f2bf(v4.x) | ((unsigned)f2bf(v4.y)<<16);
  vv.y = f2bf(v4.z) | ((unsigned)f2bf(v4.w)<<16);
  *(uint2*)(Qhi + ob) = qh;  *(uint2*)(Qlo + ob) = ql;
  *(uint2*)(Khi + ob) = kh;  *(uint2*)(Klo + ob) = kl;
  *(uint2*)(Vbf + ob) = vv;
}

// ---------------------------------------------------------------------------
// Staging helpers for the pipelined attn: global->reg issue, reg->LDS write.
// ---------------------------------------------------------------------------
__device__ __forceinline__ void stage_issue(
    const unsigned short* __restrict__ Khi_g, const unsigned short* __restrict__ Klo_g,
    const unsigned short* __restrict__ Vbf, size_t hb, int jt, int tid,
    uint2* khr, uint2* klr, ushort4* vra, ushort4* vrb)
{
  #pragma unroll
  for (int i = 0; i < 4; ++i){
    int idx = tid + i*256;
    int row = idx >> 4, c4 = idx & 15;
    size_t g = (hb + jt*64 + row)*64 + c4*4;
    khr[i] = *(const uint2*)(Khi_g + g);
    klr[i] = *(const uint2*)(Klo_g + g);
  }
  #pragma unroll
  for (int i = 0; i < 2; ++i){
    int idx = tid + i*256;
    int rp = idx & 31, d4 = idx >> 5;
    size_t g = (hb + jt*64 + 2*rp)*64 + d4*4;
    vra[i] = *(const ushort4*)(Vbf + g);
    vrb[i] = *(const ushort4*)(Vbf + g + 64);
  }
}

__device__ __forceinline__ void stage_write(char* bufc, int tid,
    const uint2* khr, const uint2* klr, const ushort4* vra, const ushort4* vrb)
{
  unsigned short* Kh = (unsigned short*)bufc;
  unsigned short* Kl = (unsigned short*)(bufc + 9216);
  unsigned* vt = (unsigned*)(bufc + 18432);
  #pragma unroll
  for (int i = 0; i < 4; ++i){
    int idx = tid + i*256;
    int row = idx >> 4, c4 = idx & 15;
    *(uint2*)(Kh + row*ST + c4*4) = khr[i];
    *(uint2*)(Kl + row*ST + c4*4) = klr[i];
  }
  #pragma unroll
  for (int i = 0; i < 2; ++i){
    int idx = tid + i*256;
    int rp = idx & 31, d4 = idx >> 5;
    vt[(d4*4+0)*36 + rp] = (unsigned)vra[i].x | ((unsigned)vrb[i].x << 16);
    vt[(d4*4+1)*36 + rp] = (unsigned)vra[i].y | ((unsigned)vrb[i].y << 16);
    vt[(d4*4+2)*36 + rp] = (unsigned)vra[i].z | ((unsigned)vrb[i].z << 16);
    vt[(d4*4+3)*36 + rp] = (unsigned)vra[i].w | ((unsigned)vrb[i].w << 16);
  }
}

// ---------------------------------------------------------------------------
// One q-tile's score + online-softmax + PV update against the staged K/V tile.
// ---------------------------------------------------------------------------
__device__ __forceinline__ void attn_tile(
    const unsigned short* __restrict__ Kh, const unsigned short* __restrict__ Kl,
    const unsigned short* __restrict__ Vt, unsigned short* __restrict__ pw,
    const bf16x8* qh, const bf16x8* ql,
    f32x4* O, float& mr, float& lr,
    bool last, int relrow, int mi, int quad)
{
  f32x4 st[4];
  #pragma unroll
  for (int mt = 0; mt < 4; ++mt) st[mt] = (f32x4){0.f,0.f,0.f,0.f};
  __builtin_amdgcn_s_setprio(1);
  #pragma unroll
  for (int mt = 0; mt < 4; ++mt){
    int krow = mt*16 + mi;
    #pragma unroll
    for (int ks = 0; ks < 2; ++ks){
      bf16x8 kh = __builtin_bit_cast(bf16x8, *(const short8*)(Kh + krow*ST + ks*32 + quad*8));
      bf16x8 kl = __builtin_bit_cast(bf16x8, *(const short8*)(Kl + krow*ST + ks*32 + quad*8));
      st[mt] = __builtin_amdgcn_mfma_f32_16x16x32_bf16(kl, qh[ks], st[mt], 0, 0, 0);
      st[mt] = __builtin_amdgcn_mfma_f32_16x16x32_bf16(kh, ql[ks], st[mt], 0, 0, 0);
      st[mt] = __builtin_amdgcn_mfma_f32_16x16x32_bf16(kh, qh[ks], st[mt], 0, 0, 0);
    }
  }
  __builtin_amdgcn_s_setprio(0);

  float tmax = -INFINITY;
  #pragma unroll
  for (int mt = 0; mt < 4; ++mt)
    #pragma unroll
    for (int r = 0; r < 4; ++r){
      float s = st[mt][r] * SCALE_F;
      if (last){
        int key = mt*16 + quad*4 + r;
        if (key > relrow) s = -INFINITY;
      }
      st[mt][r] = s;
      tmax = fmaxf(tmax, s);
    }
  tmax = fmaxf(tmax, __shfl_xor(tmax, 16));
  tmax = fmaxf(tmax, __shfl_xor(tmax, 32));
  float mnew = fmaxf(mr, tmax);
  float alpha = __expf(mr - mnew);
  mr = mnew;
  float tsum = 0.f;
  #pragma unroll
  for (int mt = 0; mt < 4; ++mt)
    #pragma unroll
    for (int r = 0; r < 4; ++r){
      float p = __expf(st[mt][r] - mnew);
      st[mt][r] = p;
      tsum += p;
    }
  tsum += __shfl_xor(tsum, 16);
  tsum += __shfl_xor(tsum, 32);
  lr = lr*alpha + tsum;

  #pragma unroll
  for (int mt = 0; mt < 4; ++mt){
    uint2 pk;
    pk.x = (unsigned)f2bf(st[mt][0]) | ((unsigned)f2bf(st[mt][1]) << 16);
    pk.y = (unsigned)f2bf(st[mt][2]) | ((unsigned)f2bf(st[mt][3]) << 16);
    *(uint2*)(pw + mi*ST + mt*16 + quad*4) = pk;
  }

  float af[4];
  #pragma unroll
  for (int r = 0; r < 4; ++r) af[r] = __shfl(alpha, quad*4 + r);
  #pragma unroll
  for (int dn = 0; dn < 4; ++dn)
    #pragma unroll
    for (int r = 0; r < 4; ++r) O[dn][r] *= af[r];

  __builtin_amdgcn_s_setprio(1);
  #pragma unroll
  for (int kt = 0; kt < 2; ++kt){
    bf16x8 pf = __builtin_bit_cast(bf16x8, *(const short8*)(pw + mi*ST + kt*32 + quad*8));
    #pragma unroll
    for (int dn = 0; dn < 4; ++dn){
      bf16x8 vf = __builtin_bit_cast(bf16x8, *(const short8*)(Vt + (dn*16 + mi)*ST + kt*32 + quad*8));
      O[dn] = __builtin_amdgcn_mfma_f32_16x16x32_bf16(pf, vf, O[dn], 0, 0, 0);
    }
  }
  __builtin_amdgcn_s_setprio(0);
}

// ---------------------------------------------------------------------------
// Paired-tile flash attention + parallel KNN + gate, double-buffered K/V LDS
// with async-stage split (T14). Grid (T/128, H, B).
// ---------------------------------------------------------------------------
__global__ __launch_bounds__(256)
void attn_knn(const unsigned short* __restrict__ Qhi, const unsigned short* __restrict__ Qlo,
              const unsigned short* __restrict__ Khi_g, const unsigned short* __restrict__ Klo_g,
              const unsigned short* __restrict__ Vbf,
              const float* __restrict__ mem_bank, const int* __restrict__ knn_idx,
              const float* __restrict__ gate_bias, unsigned short* __restrict__ comb)
{
  __shared__ __align__(16) char smpool[64512];
  float* qkvs = (float*)smpool;                            // overlay 128 x 68 fp32 (epilogue)

  const int bb = blockIdx.z, h = blockIdx.y;
  const int p = blockIdx.x;            // pair id 0..15
  const int jA = p, jB = 31 - p;
  const int tid = threadIdx.x, lane = tid & 63, wv = tid >> 6;
  const int mi = lane & 15, quad = lane >> 4;
  const int relrow = wv*16 + mi;
  const size_t hb = (size_t)(bb*H_ + h)*T_;
  unsigned short* pw = (unsigned short*)(smpool + 55296) + wv*1152;

  bf16x8 qhA[2], qlA[2], qhB[2], qlB[2];
  #pragma unroll
  for (int ks = 0; ks < 2; ++ks){
    qhA[ks] = __builtin_bit_cast(bf16x8, *(const uint4*)(Qhi + (hb + jA*64 + relrow)*64 + ks*32 + quad*8));
    qlA[ks] = __builtin_bit_cast(bf16x8, *(const uint4*)(Qlo + (hb + jA*64 + relrow)*64 + ks*32 + quad*8));
    qhB[ks] = __builtin_bit_cast(bf16x8, *(const uint4*)(Qhi + (hb + jB*64 + relrow)*64 + ks*32 + quad*8));
    qlB[ks] = __builtin_bit_cast(bf16x8, *(const uint4*)(Qlo + (hb + jB*64 + relrow)*64 + ks*32 + quad*8));
  }

  f32x4 OA[4], OB[4];
  #pragma unroll
  for (int dn = 0; dn < 4; ++dn){
    OA[dn] = (f32x4){0.f,0.f,0.f,0.f};
    OB[dn] = (f32x4){0.f,0.f,0.f,0.f};
  }
  float mA = -INFINITY, lA = 0.f, mB = -INFINITY, lB = 0.f;

  const int ntiles = jB + 1;           // >= 17 always

  // --- pipelined staging: prologue ---
  uint2 khr[4], klr[4]; ushort4 vra[2], vrb[2];
  stage_issue(Khi_g, Klo_g, Vbf, hb, 0, tid, khr, klr, vra, vrb);
  stage_write(smpool, tid, khr, klr, vra, vrb);
  stage_issue(Khi_g, Klo_g, Vbf, hb, 1, tid, khr, klr, vra, vrb);

  int cur = 0;
  for (int jt = 0; jt < ntiles; ++jt){
    __syncthreads();                    // buf[cur] writes visible; buf[cur^1] free
    if (jt + 1 < ntiles){
      stage_write(smpool + (cur^1)*27648, tid, khr, klr, vra, vrb);
      if (jt + 2 < ntiles)
        stage_issue(Khi_g, Klo_g, Vbf, hb, jt+2, tid, khr, klr, vra, vrb);
    }
    char* bufc = smpool + cur*27648;
    const unsigned short* Kh = (const unsigned short*)bufc;
    const unsigned short* Kl = (const unsigned short*)(bufc + 9216);
    const unsigned short* Vt = (const unsigned short*)(bufc + 18432);
    if (jt <= jA)
      attn_tile(Kh, Kl, Vt, pw, qhA, qlA, OA, mA, lA, jt == jA, relrow, mi, quad);
    attn_tile(Kh, Kl, Vt, pw, qhB, qlB, OB, mB, lB, jt == jB, relrow, mi, quad);
    cur ^= 1;
  }

  __syncthreads();
  {
    float liA[4], liB[4];
    #pragma unroll
    for (int r = 0; r < 4; ++r){
      liA[r] = 1.f / __shfl(lA, quad*4 + r);
      liB[r] = 1.f / __shfl(lB, quad*4 + r);
    }
    #pragma unroll
    for (int dn = 0; dn < 4; ++dn)
      #pragma unroll
      for (int r = 0; r < 4; ++r){
        qkvs[(      wv*16 + quad*4 + r)*68 + dn*16 + mi] = OA[dn][r] * liA[r];
        qkvs[(64 +  wv*16 + quad*4 + r)*68 + dn*16 + mi] = OB[dn][r] * liB[r];
      }
  }
  __syncthreads();

  // ---- parallel KNN + gate: 4-lane group per row, 16 dims per lane ----
  const float g = gate_bias[h];
  const float gq = 1.f - g;
  const int sub = lane & 3;
  const int grp = tid >> 2;          // 0..63 (row within tile)
  const int base = lane & 60;        // group base lane within wave

  #pragma unroll
  for (int it = 0; it < 2; ++it){
    const int jq = it ? jB : jA;
    const int trow = jq*64 + grp;
    const int lrow = it*64 + grp;
    const int* kidx = knn_idx + ((size_t)bb*T_ + trow)*3;
    int myidx = 0;
    if (sub < 3) myidx = kidx[sub];

    float qf[16];
    {
      const unsigned short* qp = Qhi + (hb + trow)*64 + sub*16;
      const unsigned short* lp = Qlo + (hb + trow)*64 + sub*16;
      unsigned short hs[16], ls[16];
      *(uint4*)hs     = *(const uint4*)qp;
      *(uint4*)(hs+8) = *(const uint4*)(qp+8);
      *(uint4*)ls     = *(const uint4*)lp;
      *(uint4*)(ls+8) = *(const uint4*)(lp+8);
      #pragma unroll
      for (int j = 0; j < 16; ++j) qf[j] = bf2f(hs[j]) + bf2f(ls[j]);
    }

    int idxs[3]; float dts[3]; float mx = -INFINITY;
    #pragma unroll
    for (int kk = 0; kk < 3; ++kk){
      int idx = __shfl(myidx, base + kk);
      idxs[kk] = idx;
      const float* mk = mem_bank + (((size_t)bb*M_ + idx)*2 + 0)*D_ + h*HD_ + sub*16;
      float dsum = 0.f;
      #pragma unroll
      for (int j4 = 0; j4 < 4; ++j4){
        float4 m4 = *(const float4*)(mk + j4*4);
        dsum += qf[j4*4+0]*m4.x + qf[j4*4+1]*m4.y + qf[j4*4+2]*m4.z + qf[j4*4+3]*m4.w;
      }
      dsum += __shfl_xor(dsum, 1);
      dsum += __shfl_xor(dsum, 2);
      dsum *= SCALE_F;
      dts[kk] = dsum;
      mx = fmaxf(mx, dsum);
    }
    float e0 = __expf(dts[0]-mx), e1 = __expf(dts[1]-mx), e2 = __expf(dts[2]-mx);
    float inv = 1.f/(e0+e1+e2);
    float w[3] = {e0*inv, e1*inv, e2*inv};

    float ov[16];
    #pragma unroll
    for (int j = 0; j < 16; ++j) ov[j] = 0.f;
    #pragma unroll
    for (int kk = 0; kk < 3; ++kk){
      const float* mv = mem_bank + (((size_t)bb*M_ + idxs[kk])*2 + 1)*D_ + h*HD_ + sub*16;
      #pragma unroll
      for (int j4 = 0; j4 < 4; ++j4){
        float4 m4 = *(const float4*)(mv + j4*4);
        ov[j4*4+0] += w[kk]*m4.x;
        ov[j4*4+1] += w[kk]*m4.y;
        ov[j4*4+2] += w[kk]*m4.z;
        ov[j4*4+3] += w[kk]*m4.w;
      }
    }

    unsigned short os[16];
    #pragma unroll
    for (int j = 0; j < 16; ++j){
      float qkv = qkvs[lrow*68 + sub*16 + j];
      os[j] = f2bf(ov[j]*g + qkv*gq);
    }
    unsigned short* op = comb + ((size_t)bb*T_ + trow)*D_ + h*HD_ + sub*16;
    *(uint4*)op     = *(uint4*)os;
    *(uint4*)(op+8) = *(uint4*)(os+8);
  }
}

extern "C" void kernel_launch(void* const* d_in, const int* in_sizes, int n_in,
                              void* d_out, int out_size, void* d_ws, size_t ws_size,
                              hipStream_t stream)
{
  (void)in_sizes; (void)n_in; (void)out_size; (void)ws_size;
  const float* x    = (const float*)d_in[0];
  const float* Wq   = (const float*)d_in[1];
  const float* bq   = (const float*)d_in[2];
  const float* Wk   = (const float*)d_in[3];
  const float* bk   = (const float*)d_in[4];
  const float* Wv   = (const float*)d_in[5];
  const float* bv   = (const float*)d_in[6];
  const float* Wo   = (const float*)d_in[7];
  const float* bo   = (const float*)d_in[8];
  const float* gate = (const float*)d_in[9];
  const float* mem  = (const float*)d_in[10];
  const int*   knn  = (const int*)d_in[11];

  char* ws = (char*)d_ws;
  float*          P    = (float*)ws;                               // 48 MB
  unsigned short* comb = (unsigned short*)ws;                      // 8 MB, aliases P
  unsigned short* Qhi  = (unsigned short*)(ws +  50331648);
  unsigned short* Qlo  = (unsigned short*)(ws +  58720256);
  unsigned short* Khi  = (unsigned short*)(ws +  67108864);
  unsigned short* Klo  = (unsigned short*)(ws +  75497472);
  unsigned short* Vbf  = (unsigned short*)(ws +  83886080);
  unsigned short* Xhi  = (unsigned short*)(ws +  92274688);
  unsigned short* Xlo  = (unsigned short*)(ws + 100663296);
  unsigned short* Whi  = (unsigned short*)(ws + 109051904);        // 3072x1024
  unsigned short* Wlo  = (unsigned short*)(ws + 115343360);        // 2048x1024 (q,k only)
  unsigned short* Wohi = (unsigned short*)(ws + 119537664);        // 1024x1024

  cvt_all<<<8192, 256, 0, stream>>>(x, Wq, Wk, Wv, Wo, Xhi, Xlo, Whi, Wlo, Wohi);
  gemm_lds<true><<<dim3(24, 32), 256, 0, stream>>>(Xhi, Xlo, Whi, Wlo, bq, bk, bv, P, LDP);
  norm_split<<<4096, 256, 0, stream>>>(P, Qhi, Qlo, Khi, Klo, Vbf);
  attn_knn<<<dim3(T_/128, H_, B_), 256, 0, stream>>>(Qhi, Qlo, Khi, Klo, Vbf,
                                                     mem, knn, gate, comb);
  gemm_lds<false><<<dim3(8, 32), 256, 0, stream>>>(comb, nullptr, Wohi, nullptr,
                                                   bo, bo, bo, (float*)d_out, D_);
}

// Round 5
// 561.968 us; speedup vs baseline: 1.0632x; 1.0632x over previous
//
#include <hip/hip_runtime.h>
#include <math.h>

#define B_ 2
#define T_ 2048
#define D_ 1024
#define H_ 16
#define HD_ 64
#define M_ 16384
#define SCALE_F 4096.0f
#define LDP 3072
#define ST 72            // LDS row stride (shorts) for attn tiles

using short8 = __attribute__((ext_vector_type(8))) short;
using bf16x8 = __attribute__((ext_vector_type(8))) __bf16;
using f32x4  = __attribute__((ext_vector_type(4))) float;

__device__ __forceinline__ unsigned short f2bf(float x){
  unsigned u = __builtin_bit_cast(unsigned, x);
  u += 0x7fffu + ((u >> 16) & 1u);          // RNE
  return (unsigned short)(u >> 16);
}
__device__ __forceinline__ float bf2f(unsigned short h){
  unsigned u = ((unsigned)h) << 16;
  return __builtin_bit_cast(float, u);
}

__device__ __forceinline__ float wsum(float v){
  #pragma unroll
  for (int off = 32; off; off >>= 1) v += __shfl_xor(v, off);
  return v;
}

__device__ __forceinline__ void ld_g2l16(const unsigned short* g, unsigned short* l){
  __builtin_amdgcn_global_load_lds(
      (const __attribute__((address_space(1))) void*)g,
      (__attribute__((address_space(3))) void*)l, 16, 0, 0);
}

// ---------------------------------------------------------------------------
// One-shot fp32 -> bf16 hi/lo conversion for all GEMM operands.
// ---------------------------------------------------------------------------
__global__ __launch_bounds__(256)
void cvt_all(const float* __restrict__ x, const float* __restrict__ Wq,
             const float* __restrict__ Wk, const float* __restrict__ Wv,
             const float* __restrict__ Wo,
             unsigned short* __restrict__ Xhi, unsigned short* __restrict__ Xlo,
             unsigned short* __restrict__ Whi, unsigned short* __restrict__ Wlo,
             unsigned short* __restrict__ Wohi)
{
  const int i = blockIdx.x*256 + threadIdx.x;
  const float* src; unsigned short* hi; unsigned short* lo = nullptr; int rel;
  if      (i < 1048576){ src = x;  hi = Xhi;            lo = Xlo;            rel = i; }
  else if (i < 1310720){ src = Wq; hi = Whi;            lo = Wlo;            rel = i - 1048576; }
  else if (i < 1572864){ src = Wk; hi = Whi + 1048576;  lo = Wlo + 1048576;  rel = i - 1310720; }
  else if (i < 1835008){ src = Wv; hi = Whi + 2097152;                       rel = i - 1572864; }
  else                 { src = Wo; hi = Wohi;                                rel = i - 1835008; }
  float4 v = *(const float4*)(src + (size_t)rel*4);
  unsigned short h0=f2bf(v.x), h1=f2bf(v.y), h2=f2bf(v.z), h3=f2bf(v.w);
  uint2 hh; hh.x = (unsigned)h0 | ((unsigned)h1 << 16);
            hh.y = (unsigned)h2 | ((unsigned)h3 << 16);
  *(uint2*)(hi + (size_t)rel*4) = hh;
  if (lo){
    uint2 ll;
    ll.x = (unsigned)f2bf(v.x-bf2f(h0)) | ((unsigned)f2bf(v.y-bf2f(h1)) << 16);
    ll.y = (unsigned)f2bf(v.z-bf2f(h2)) | ((unsigned)f2bf(v.w-bf2f(h3)) << 16);
    *(uint2*)(lo + (size_t)rel*4) = ll;
  }
}

// ---------------------------------------------------------------------------
// m97-structure GEMM (round-2-measured version, reverted): all four operand
// tiles staged via global_load_lds. XCD-chunked block swizzle (T1).
// ---------------------------------------------------------------------------
template<bool COMP>
__global__ __launch_bounds__(256)
void gemm_lds(const unsigned short* __restrict__ Ahi_g, const unsigned short* __restrict__ Alo_g,
              const unsigned short* __restrict__ Bhi_g, const unsigned short* __restrict__ Blo_g,
              const float* __restrict__ bias0, const float* __restrict__ bias1,
              const float* __restrict__ bias2,
              float* __restrict__ C, int ldc)
{
  __shared__ __align__(16) unsigned short Ah[128*32];
  __shared__ __align__(16) unsigned short Bh[128*32];
  __shared__ __align__(16) unsigned short Al[COMP ? 128*32 : 8];
  __shared__ __align__(16) unsigned short Bl[COMP ? 128*32 : 8];

  const int tid = threadIdx.x, lane = tid & 63, wv = tid >> 6;
  const int wm = wv >> 1, wn = wv & 1;
  const int mi = lane & 15, quad = lane >> 4;

  // bijective XCD swizzle (nwg % 8 == 0 for both instantiations)
  int bid = blockIdx.y*gridDim.x + blockIdx.x;
  const int cpx = (gridDim.x*gridDim.y) >> 3;
  bid = (bid & 7)*cpx + (bid >> 3);
  const int n0 = (bid % gridDim.x) * 128;
  const int m0 = (bid / gridDim.x) * 128;

  const int seg = n0 >> 10;
  const float* bias = (seg == 0) ? bias0 : (seg == 1) ? bias1 : bias2;
  const int nw = n0 & 1023;
  const bool comp = COMP && (seg < 2);

  f32x4 acc[4][4];
  #pragma unroll
  for (int a = 0; a < 4; ++a)
    #pragma unroll
    for (int b = 0; b < 4; ++b)
      acc[a][b] = (f32x4){0.f, 0.f, 0.f, 0.f};

  for (int k0 = 0; k0 < 1024; k0 += 32){
    __syncthreads();
    #pragma unroll
    for (int t = 0; t < 2; ++t){
      int j = wv*128 + t*64 + lane;
      int row = j >> 2, c16 = j & 3;
      size_t ga = (size_t)(m0 + row)*1024 + k0 + c16*8;
      size_t gb = (size_t)(n0 + row)*1024 + k0 + c16*8;
      ld_g2l16(Ahi_g + ga, Ah + j*8);
      ld_g2l16(Bhi_g + gb, Bh + j*8);
      if (comp){
        ld_g2l16(Alo_g + ga, Al + j*8);
        ld_g2l16(Blo_g + gb, Bl + j*8);
      }
    }
    __syncthreads();

    bf16x8 ah[4], al[4];
    #pragma unroll
    for (int a = 0; a < 4; ++a){
      int r = wm*64 + a*16 + mi;
      ah[a] = __builtin_bit_cast(bf16x8, *(const short8*)(Ah + r*32 + quad*8));
      if (comp)
        al[a] = __builtin_bit_cast(bf16x8, *(const short8*)(Al + r*32 + quad*8));
    }
    #pragma unroll
    for (int b = 0; b < 4; ++b){
      int r = wn*64 + b*16 + mi;
      bf16x8 bh = __builtin_bit_cast(bf16x8, *(const short8*)(Bh + r*32 + quad*8));
      if (comp){
        bf16x8 bl = __builtin_bit_cast(bf16x8, *(const short8*)(Bl + r*32 + quad*8));
        #pragma unroll
        for (int a = 0; a < 4; ++a){
          acc[a][b] = __builtin_amdgcn_mfma_f32_16x16x32_bf16(al[a], bh, acc[a][b], 0, 0, 0);
          acc[a][b] = __builtin_amdgcn_mfma_f32_16x16x32_bf16(ah[a], bl, acc[a][b], 0, 0, 0);
          acc[a][b] = __builtin_amdgcn_mfma_f32_16x16x32_bf16(ah[a], bh, acc[a][b], 0, 0, 0);
        }
      } else {
        #pragma unroll
        for (int a = 0; a < 4; ++a)
          acc[a][b] = __builtin_amdgcn_mfma_f32_16x16x32_bf16(ah[a], bh, acc[a][b], 0, 0, 0);
      }
    }
  }
  #pragma unroll
  for (int a = 0; a < 4; ++a)
    #pragma unroll
    for (int b = 0; b < 4; ++b)
      #pragma unroll
      for (int r = 0; r < 4; ++r){
        int row  = m0 + wm*64 + a*16 + quad*4 + r;
        int coll = wn*64 + b*16 + mi;
        C[(size_t)row*ldc + n0 + coll] = acc[a][b][r] + bias[nw + coll];
      }
}

// ---------------------------------------------------------------------------
// Normalize q,k rows of P; emit head-major bf16: Qhi/Qlo/Khi/Klo/Vbf
// ---------------------------------------------------------------------------
__global__ __launch_bounds__(256)
void norm_split(const float* __restrict__ P,
                unsigned short* __restrict__ Qhi, unsigned short* __restrict__ Qlo,
                unsigned short* __restrict__ Khi, unsigned short* __restrict__ Klo,
                unsigned short* __restrict__ Vbf)
{
  const int row = blockIdx.x, tid = threadIdx.x;
  const int bb = row >> 11, t = row & 2047;
  const int lane = tid & 63, wv = tid >> 6;
  const size_t base = (size_t)row * LDP;
  float4 q4 = *(const float4*)(P + base + tid*4);
  float4 k4 = *(const float4*)(P + base + 1024 + tid*4);
  float4 v4 = *(const float4*)(P + base + 2048 + tid*4);
  float sq = wsum(q4.x*q4.x + q4.y*q4.y + q4.z*q4.z + q4.w*q4.w);
  float sk = wsum(k4.x*k4.x + k4.y*k4.y + k4.z*k4.z + k4.w*k4.w);
  __shared__ float rq[4], rk[4];
  if (lane == 0){ rq[wv] = sq; rk[wv] = sk; }
  __syncthreads();
  float cq = 1.f / fmaxf(sqrtf(rq[0]+rq[1]+rq[2]+rq[3]), 1e-12f);
  float ck = 1.f / fmaxf(sqrtf(rk[0]+rk[1]+rk[2]+rk[3]), 1e-12f);
  float qf[4] = {q4.x*cq, q4.y*cq, q4.z*cq, q4.w*cq};
  float kf[4] = {k4.x*ck, k4.y*ck, k4.z*ck, k4.w*ck};

  const int h = tid >> 4, d0 = (tid & 15)*4;
  const size_t ob = ((size_t)(bb*H_ + h)*T_ + t)*64 + d0;

  uint2 qh, ql, kh, kl, vv;
  unsigned short t0,t1,t2,t3;
  t0=f2bf(qf[0]); t1=f2bf(qf[1]); t2=f2bf(qf[2]); t3=f2bf(qf[3]);
  qh.x = t0 | ((unsigned)t1<<16); qh.y = t2 | ((unsigned)t3<<16);
  ql.x = f2bf(qf[0]-bf2f(t0)) | ((unsigned)f2bf(qf[1]-bf2f(t1))<<16);
  ql.y = f2bf(qf[2]-bf2f(t2)) | ((unsigned)f2bf(qf[3]-bf2f(t3))<<16);
  t0=f2bf(kf[0]); t1=f2bf(kf[1]); t2=f2bf(kf[2]); t3=f2bf(kf[3]);
  kh.x = t0 | ((unsigned)t1<<16); kh.y = t2 | ((unsigned)t3<<16);
  kl.x = f2bf(kf[0]-bf2f(t0)) | ((unsigned)f2bf(kf[1]-bf2f(t1))<<16);
  kl.y = f2bf(kf[2]-bf2f(t2)) | ((unsigned)f2bf(kf[3]-bf2f(t3))<<16);
  vv.x = f2bf(v4.x) | ((unsigned)f2bf(v4.y)<<16);
  vv.y = f2bf(v4.z) | ((unsigned)f2bf(v4.w)<<16);
  *(uint2*)(Qhi + ob) = qh;  *(uint2*)(Qlo + ob) = ql;
  *(uint2*)(Khi + ob) = kh;  *(uint2*)(Klo + ob) = kl;
  *(uint2*)(Vbf + ob) = vv;
}

// ---------------------------------------------------------------------------
// Staging helpers for the pipelined attn: global->reg issue, reg->LDS write.
// ---------------------------------------------------------------------------
__device__ __forceinline__ void stage_issue(
    const unsigned short* __restrict__ Khi_g, const unsigned short* __restrict__ Klo_g,
    const unsigned short* __restrict__ Vbf, size_t hb, int jt, int tid,
    uint2* khr, uint2* klr, ushort4* vra, ushort4* vrb)
{
  #pragma unroll
  for (int i = 0; i < 4; ++i){
    int idx = tid + i*256;
    int row = idx >> 4, c4 = idx & 15;
    size_t g = (hb + jt*64 + row)*64 + c4*4;
    khr[i] = *(const uint2*)(Khi_g + g);
    klr[i] = *(const uint2*)(Klo_g + g);
  }
  #pragma unroll
  for (int i = 0; i < 2; ++i){
    int idx = tid + i*256;
    int rp = idx & 31, d4 = idx >> 5;
    size_t g = (hb + jt*64 + 2*rp)*64 + d4*4;
    vra[i] = *(const ushort4*)(Vbf + g);
    vrb[i] = *(const ushort4*)(Vbf + g + 64);
  }
}

__device__ __forceinline__ void stage_write(char* bufc, int tid,
    const uint2* khr, const uint2* klr, const ushort4* vra, const ushort4* vrb)
{
  unsigned short* Kh = (unsigned short*)bufc;
  unsigned short* Kl = (unsigned short*)(bufc + 9216);
  unsigned* vt = (unsigned*)(bufc + 18432);
  #pragma unroll
  for (int i = 0; i < 4; ++i){
    int idx = tid + i*256;
    int row = idx >> 4, c4 = idx & 15;
    *(uint2*)(Kh + row*ST + c4*4) = khr[i];
    *(uint2*)(Kl + row*ST + c4*4) = klr[i];
  }
  #pragma unroll
  for (int i = 0; i < 2; ++i){
    int idx = tid + i*256;
    int rp = idx & 31, d4 = idx >> 5;
    vt[(d4*4+0)*36 + rp] = (unsigned)vra[i].x | ((unsigned)vrb[i].x << 16);
    vt[(d4*4+1)*36 + rp] = (unsigned)vra[i].y | ((unsigned)vrb[i].y << 16);
    vt[(d4*4+2)*36 + rp] = (unsigned)vra[i].z | ((unsigned)vrb[i].z << 16);
    vt[(d4*4+3)*36 + rp] = (unsigned)vra[i].w | ((unsigned)vrb[i].w << 16);
  }
}

// ---------------------------------------------------------------------------
// One q-tile's score + online-softmax + PV update against the staged K/V tile.
// ---------------------------------------------------------------------------
__device__ __forceinline__ void attn_tile(
    const unsigned short* __restrict__ Kh, const unsigned short* __restrict__ Kl,
    const unsigned short* __restrict__ Vt, unsigned short* __restrict__ pw,
    const bf16x8* qh, const bf16x8* ql,
    f32x4* O, float& mr, float& lr,
    bool last, int relrow, int mi, int quad)
{
  f32x4 st[4];
  #pragma unroll
  for (int mt = 0; mt < 4; ++mt) st[mt] = (f32x4){0.f,0.f,0.f,0.f};
  __builtin_amdgcn_s_setprio(1);
  #pragma unroll
  for (int mt = 0; mt < 4; ++mt){
    int krow = mt*16 + mi;
    #pragma unroll
    for (int ks = 0; ks < 2; ++ks){
      bf16x8 kh = __builtin_bit_cast(bf16x8, *(const short8*)(Kh + krow*ST + ks*32 + quad*8));
      bf16x8 kl = __builtin_bit_cast(bf16x8, *(const short8*)(Kl + krow*ST + ks*32 + quad*8));
      st[mt] = __builtin_amdgcn_mfma_f32_16x16x32_bf16(kl, qh[ks], st[mt], 0, 0, 0);
      st[mt] = __builtin_amdgcn_mfma_f32_16x16x32_bf16(kh, ql[ks], st[mt], 0, 0, 0);
      st[mt] = __builtin_amdgcn_mfma_f32_16x16x32_bf16(kh, qh[ks], st[mt], 0, 0, 0);
    }
  }
  __builtin_amdgcn_s_setprio(0);

  float tmax = -INFINITY;
  #pragma unroll
  for (int mt = 0; mt < 4; ++mt)
    #pragma unroll
    for (int r = 0; r < 4; ++r){
      float s = st[mt][r] * SCALE_F;
      if (last){
        int key = mt*16 + quad*4 + r;
        if (key > relrow) s = -INFINITY;
      }
      st[mt][r] = s;
      tmax = fmaxf(tmax, s);
    }
  tmax = fmaxf(tmax, __shfl_xor(tmax, 16));
  tmax = fmaxf(tmax, __shfl_xor(tmax, 32));
  float mnew = fmaxf(mr, tmax);
  float alpha = __expf(mr - mnew);
  mr = mnew;
  float tsum = 0.f;
  #pragma unroll
  for (int mt = 0; mt < 4; ++mt)
    #pragma unroll
    for (int r = 0; r < 4; ++r){
      float p = __expf(st[mt][r] - mnew);
      st[mt][r] = p;
      tsum += p;
    }
  tsum += __shfl_xor(tsum, 16);
  tsum += __shfl_xor(tsum, 32);
  lr = lr*alpha + tsum;

  #pragma unroll
  for (int mt = 0; mt < 4; ++mt){
    uint2 pk;
    pk.x = (unsigned)f2bf(st[mt][0]) | ((unsigned)f2bf(st[mt][1]) << 16);
    pk.y = (unsigned)f2bf(st[mt][2]) | ((unsigned)f2bf(st[mt][3]) << 16);
    *(uint2*)(pw + mi*ST + mt*16 + quad*4) = pk;
  }

  float af[4];
  #pragma unroll
  for (int r = 0; r < 4; ++r) af[r] = __shfl(alpha, quad*4 + r);
  #pragma unroll
  for (int dn = 0; dn < 4; ++dn)
    #pragma unroll
    for (int r = 0; r < 4; ++r) O[dn][r] *= af[r];

  __builtin_amdgcn_s_setprio(1);
  #pragma unroll
  for (int kt = 0; kt < 2; ++kt){
    bf16x8 pf = __builtin_bit_cast(bf16x8, *(const short8*)(pw + mi*ST + kt*32 + quad*8));
    #pragma unroll
    for (int dn = 0; dn < 4; ++dn){
      bf16x8 vf = __builtin_bit_cast(bf16x8, *(const short8*)(Vt + (dn*16 + mi)*ST + kt*32 + quad*8));
      O[dn] = __builtin_amdgcn_mfma_f32_16x16x32_bf16(pf, vf, O[dn], 0, 0, 0);
    }
  }
  __builtin_amdgcn_s_setprio(0);
}

// ---------------------------------------------------------------------------
// Paired-tile flash attention + parallel KNN + gate, double-buffered K/V LDS
// with async-stage split (T14). Grid (T/128, H, B).
// KNN tail: idx prefetched before the flash loop; all 24 mk+mv gathers issued
// upfront per iteration (one HBM round-trip instead of two serial ones).
// ---------------------------------------------------------------------------
__global__ __launch_bounds__(256)
void attn_knn(const unsigned short* __restrict__ Qhi, const unsigned short* __restrict__ Qlo,
              const unsigned short* __restrict__ Khi_g, const unsigned short* __restrict__ Klo_g,
              const unsigned short* __restrict__ Vbf,
              const float* __restrict__ mem_bank, const int* __restrict__ knn_idx,
              const float* __restrict__ gate_bias, unsigned short* __restrict__ comb)
{
  __shared__ __align__(16) char smpool[64512];
  float* qkvs = (float*)smpool;                            // overlay 128 x 68 fp32 (epilogue)

  const int bb = blockIdx.z, h = blockIdx.y;
  const int p = blockIdx.x;            // pair id 0..15
  const int jA = p, jB = 31 - p;
  const int tid = threadIdx.x, lane = tid & 63, wv = tid >> 6;
  const int mi = lane & 15, quad = lane >> 4;
  const int relrow = wv*16 + mi;
  const size_t hb = (size_t)(bb*H_ + h)*T_;
  unsigned short* pw = (unsigned short*)(smpool + 55296) + wv*1152;

  // KNN epilogue geometry + idx prefetch (2 VGPR, breaks the idx->mk chain)
  const int sub = lane & 3;
  const int grp = tid >> 2;          // 0..63 (row within tile)
  const int base = lane & 60;        // group base lane within wave
  int idxP[2];
  idxP[0] = (sub < 3) ? knn_idx[((size_t)bb*T_ + jA*64 + grp)*3 + sub] : 0;
  idxP[1] = (sub < 3) ? knn_idx[((size_t)bb*T_ + jB*64 + grp)*3 + sub] : 0;

  bf16x8 qhA[2], qlA[2], qhB[2], qlB[2];
  #pragma unroll
  for (int ks = 0; ks < 2; ++ks){
    qhA[ks] = __builtin_bit_cast(bf16x8, *(const uint4*)(Qhi + (hb + jA*64 + relrow)*64 + ks*32 + quad*8));
    qlA[ks] = __builtin_bit_cast(bf16x8, *(const uint4*)(Qlo + (hb + jA*64 + relrow)*64 + ks*32 + quad*8));
    qhB[ks] = __builtin_bit_cast(bf16x8, *(const uint4*)(Qhi + (hb + jB*64 + relrow)*64 + ks*32 + quad*8));
    qlB[ks] = __builtin_bit_cast(bf16x8, *(const uint4*)(Qlo + (hb + jB*64 + relrow)*64 + ks*32 + quad*8));
  }

  f32x4 OA[4], OB[4];
  #pragma unroll
  for (int dn = 0; dn < 4; ++dn){
    OA[dn] = (f32x4){0.f,0.f,0.f,0.f};
    OB[dn] = (f32x4){0.f,0.f,0.f,0.f};
  }
  float mA = -INFINITY, lA = 0.f, mB = -INFINITY, lB = 0.f;

  const int ntiles = jB + 1;           // >= 17 always

  // --- pipelined staging: prologue ---
  uint2 khr[4], klr[4]; ushort4 vra[2], vrb[2];
  stage_issue(Khi_g, Klo_g, Vbf, hb, 0, tid, khr, klr, vra, vrb);
  stage_write(smpool, tid, khr, klr, vra, vrb);
  stage_issue(Khi_g, Klo_g, Vbf, hb, 1, tid, khr, klr, vra, vrb);

  int cur = 0;
  for (int jt = 0; jt < ntiles; ++jt){
    __syncthreads();                    // buf[cur] writes visible; buf[cur^1] free
    if (jt + 1 < ntiles){
      stage_write(smpool + (cur^1)*27648, tid, khr, klr, vra, vrb);
      if (jt + 2 < ntiles)
        stage_issue(Khi_g, Klo_g, Vbf, hb, jt+2, tid, khr, klr, vra, vrb);
    }
    char* bufc = smpool + cur*27648;
    const unsigned short* Kh = (const unsigned short*)bufc;
    const unsigned short* Kl = (const unsigned short*)(bufc + 9216);
    const unsigned short* Vt = (const unsigned short*)(bufc + 18432);
    if (jt <= jA)
      attn_tile(Kh, Kl, Vt, pw, qhA, qlA, OA, mA, lA, jt == jA, relrow, mi, quad);
    attn_tile(Kh, Kl, Vt, pw, qhB, qlB, OB, mB, lB, jt == jB, relrow, mi, quad);
    cur ^= 1;
  }

  __syncthreads();
  {
    float liA[4], liB[4];
    #pragma unroll
    for (int r = 0; r < 4; ++r){
      liA[r] = 1.f / __shfl(lA, quad*4 + r);
      liB[r] = 1.f / __shfl(lB, quad*4 + r);
    }
    #pragma unroll
    for (int dn = 0; dn < 4; ++dn)
      #pragma unroll
      for (int r = 0; r < 4; ++r){
        qkvs[(      wv*16 + quad*4 + r)*68 + dn*16 + mi] = OA[dn][r] * liA[r];
        qkvs[(64 +  wv*16 + quad*4 + r)*68 + dn*16 + mi] = OB[dn][r] * liB[r];
      }
  }
  __syncthreads();

  // ---- parallel KNN + gate: 4-lane group per row, 16 dims per lane ----
  const float g = gate_bias[h];
  const float gq = 1.f - g;

  #pragma unroll
  for (int it = 0; it < 2; ++it){
    const int jq = it ? jB : jA;
    const int trow = jq*64 + grp;
    const int lrow = it*64 + grp;

    int idxs[3];
    #pragma unroll
    for (int kk = 0; kk < 3; ++kk) idxs[kk] = __shfl(idxP[it], base + kk);

    // issue ALL gather loads upfront (mk + mv are independent of the softmax)
    float4 mk4[3][4], mv4[3][4];
    #pragma unroll
    for (int kk = 0; kk < 3; ++kk){
      const float* mk = mem_bank + (((size_t)bb*M_ + idxs[kk])*2 + 0)*D_ + h*HD_ + sub*16;
      const float* mv = mem_bank + (((size_t)bb*M_ + idxs[kk])*2 + 1)*D_ + h*HD_ + sub*16;
      #pragma unroll
      for (int j4 = 0; j4 < 4; ++j4){
        mk4[kk][j4] = *(const float4*)(mk + j4*4);
        mv4[kk][j4] = *(const float4*)(mv + j4*4);
      }
    }

    float qf[16];
    {
      const unsigned short* qp = Qhi + (hb + trow)*64 + sub*16;
      const unsigned short* lp = Qlo + (hb + trow)*64 + sub*16;
      unsigned short hs[16], ls[16];
      *(uint4*)hs     = *(const uint4*)qp;
      *(uint4*)(hs+8) = *(const uint4*)(qp+8);
      *(uint4*)ls     = *(const uint4*)lp;
      *(uint4*)(ls+8) = *(const uint4*)(lp+8);
      #pragma unroll
      for (int j = 0; j < 16; ++j) qf[j] = bf2f(hs[j]) + bf2f(ls[j]);
    }

    float dts[3]; float mx = -INFINITY;
    #pragma unroll
    for (int kk = 0; kk < 3; ++kk){
      float dsum = 0.f;
      #pragma unroll
      for (int j4 = 0; j4 < 4; ++j4){
        float4 m4 = mk4[kk][j4];
        dsum += qf[j4*4+0]*m4.x + qf[j4*4+1]*m4.y + qf[j4*4+2]*m4.z + qf[j4*4+3]*m4.w;
      }
      dsum += __shfl_xor(dsum, 1);
      dsum += __shfl_xor(dsum, 2);
      dsum *= SCALE_F;
      dts[kk] = dsum;
      mx = fmaxf(mx, dsum);
    }
    float e0 = __expf(dts[0]-mx), e1 = __expf(dts[1]-mx), e2 = __expf(dts[2]-mx);
    float inv = 1.f/(e0+e1+e2);
    float w[3] = {e0*inv, e1*inv, e2*inv};

    float ov[16];
    #pragma unroll
    for (int j = 0; j < 16; ++j) ov[j] = 0.f;
    #pragma unroll
    for (int kk = 0; kk < 3; ++kk){
      #pragma unroll
      for (int j4 = 0; j4 < 4; ++j4){
        float4 m4 = mv4[kk][j4];
        ov[j4*4+0] += w[kk]*m4.x;
        ov[j4*4+1] += w[kk]*m4.y;
        ov[j4*4+2] += w[kk]*m4.z;
        ov[j4*4+3] += w[kk]*m4.w;
      }
    }

    unsigned short os[16];
    #pragma unroll
    for (int j = 0; j < 16; ++j){
      float qkv = qkvs[lrow*68 + sub*16 + j];
      os[j] = f2bf(ov[j]*g + qkv*gq);
    }
    unsigned short* op = comb + ((size_t)bb*T_ + trow)*D_ + h*HD_ + sub*16;
    *(uint4*)op     = *(uint4*)os;
    *(uint4*)(op+8) = *(uint4*)(os+8);
  }
}

extern "C" void kernel_launch(void* const* d_in, const int* in_sizes, int n_in,
                              void* d_out, int out_size, void* d_ws, size_t ws_size,
                              hipStream_t stream)
{
  (void)in_sizes; (void)n_in; (void)out_size; (void)ws_size;
  const float* x    = (const float*)d_in[0];
  const float* Wq   = (const float*)d_in[1];
  const float* bq   = (const float*)d_in[2];
  const float* Wk   = (const float*)d_in[3];
  const float* bk   = (const float*)d_in[4];
  const float* Wv   = (const float*)d_in[5];
  const float* bv   = (const float*)d_in[6];
  const float* Wo   = (const float*)d_in[7];
  const float* bo   = (const float*)d_in[8];
  const float* gate = (const float*)d_in[9];
  const float* mem  = (const float*)d_in[10];
  const int*   knn  = (const int*)d_in[11];

  char* ws = (char*)d_ws;
  float*          P    = (float*)ws;                               // 48 MB
  unsigned short* comb = (unsigned short*)ws;                      // 8 MB, aliases P
  unsigned short* Qhi  = (unsigned short*)(ws +  50331648);
  unsigned short* Qlo  = (unsigned short*)(ws +  58720256);
  unsigned short* Khi  = (unsigned short*)(ws +  67108864);
  unsigned short* Klo  = (unsigned short*)(ws +  75497472);
  unsigned short* Vbf  = (unsigned short*)(ws +  83886080);
  unsigned short* Xhi  = (unsigned short*)(ws +  92274688);
  unsigned short* Xlo  = (unsigned short*)(ws + 100663296);
  unsigned short* Whi  = (unsigned short*)(ws + 109051904);        // 3072x1024
  unsigned short* Wlo  = (unsigned short*)(ws + 115343360);        // 2048x1024 (q,k only)
  unsigned short* Wohi = (unsigned short*)(ws + 119537664);        // 1024x1024

  cvt_all<<<8192, 256, 0, stream>>>(x, Wq, Wk, Wv, Wo, Xhi, Xlo, Whi, Wlo, Wohi);
  gemm_lds<true><<<dim3(24, 32), 256, 0, stream>>>(Xhi, Xlo, Whi, Wlo, bq, bk, bv, P, LDP);
  norm_split<<<4096, 256, 0, stream>>>(P, Qhi, Qlo, Khi, Klo, Vbf);
  attn_knn<<<dim3(T_/128, H_, B_), 256, 0, stream>>>(Qhi, Qlo, Khi, Klo, Vbf,
                                                     mem, knn, gate, comb);
  gemm_lds<false><<<dim3(8, 32), 256, 0, stream>>>(comb, nullptr, Wohi, nullptr,
                                                   bo, bo, bo, (float*)d_out, D_);
}

// Round 7
// 554.877 us; speedup vs baseline: 1.0767x; 1.0128x over previous
//
#include <hip/hip_runtime.h>
#include <math.h>

#define B_ 2
#define T_ 2048
#define D_ 1024
#define H_ 16
#define HD_ 64
#define M_ 16384
#define SCALE_F 4096.0f
#define LDP 3072
#define ST 72            // LDS row stride (shorts) for attn tiles

using short8 = __attribute__((ext_vector_type(8))) short;
using bf16x8 = __attribute__((ext_vector_type(8))) __bf16;
using f32x4  = __attribute__((ext_vector_type(4))) float;

__device__ __forceinline__ unsigned short f2bf(float x){
  unsigned u = __builtin_bit_cast(unsigned, x);
  u += 0x7fffu + ((u >> 16) & 1u);          // RNE
  return (unsigned short)(u >> 16);
}
__device__ __forceinline__ float bf2f(unsigned short h){
  unsigned u = ((unsigned)h) << 16;
  return __builtin_bit_cast(float, u);
}

__device__ __forceinline__ float wsum(float v){
  #pragma unroll
  for (int off = 32; off; off >>= 1) v += __shfl_xor(v, off);
  return v;
}

__device__ __forceinline__ void ld_g2l16(const unsigned short* g, unsigned short* l){
  __builtin_amdgcn_global_load_lds(
      (const __attribute__((address_space(1))) void*)g,
      (__attribute__((address_space(3))) void*)l, 16, 0, 0);
}

// ---------------------------------------------------------------------------
// One-shot fp32 -> bf16 hi/lo conversion for all GEMM operands.
// ---------------------------------------------------------------------------
__global__ __launch_bounds__(256)
void cvt_all(const float* __restrict__ x, const float* __restrict__ Wq,
             const float* __restrict__ Wk, const float* __restrict__ Wv,
             const float* __restrict__ Wo,
             unsigned short* __restrict__ Xhi, unsigned short* __restrict__ Xlo,
             unsigned short* __restrict__ Whi, unsigned short* __restrict__ Wlo,
             unsigned short* __restrict__ Wohi)
{
  const int i = blockIdx.x*256 + threadIdx.x;
  const float* src; unsigned short* hi; unsigned short* lo = nullptr; int rel;
  if      (i < 1048576){ src = x;  hi = Xhi;            lo = Xlo;            rel = i; }
  else if (i < 1310720){ src = Wq; hi = Whi;            lo = Wlo;            rel = i - 1048576; }
  else if (i < 1572864){ src = Wk; hi = Whi + 1048576;  lo = Wlo + 1048576;  rel = i - 1310720; }
  else if (i < 1835008){ src = Wv; hi = Whi + 2097152;                       rel = i - 1572864; }
  else                 { src = Wo; hi = Wohi;                                rel = i - 1835008; }
  float4 v = *(const float4*)(src + (size_t)rel*4);
  unsigned short h0=f2bf(v.x), h1=f2bf(v.y), h2=f2bf(v.z), h3=f2bf(v.w);
  uint2 hh; hh.x = (unsigned)h0 | ((unsigned)h1 << 16);
            hh.y = (unsigned)h2 | ((unsigned)h3 << 16);
  *(uint2*)(hi + (size_t)rel*4) = hh;
  if (lo){
    uint2 ll;
    ll.x = (unsigned)f2bf(v.x-bf2f(h0)) | ((unsigned)f2bf(v.y-bf2f(h1)) << 16);
    ll.y = (unsigned)f2bf(v.z-bf2f(h2)) | ((unsigned)f2bf(v.w-bf2f(h3)) << 16);
    *(uint2*)(lo + (size_t)rel*4) = ll;
  }
}

// ---------------------------------------------------------------------------
// m97-structure GEMM (round-2-measured). XCD-chunked block swizzle (T1).
// COMP path: seg==2 (v) writes bf16 head-major direct to Vout (value path
// identical to the old P->norm_split->f2bf route); seg 0/1 write fp32 P.
// ---------------------------------------------------------------------------
template<bool COMP>
__global__ __launch_bounds__(256)
void gemm_lds(const unsigned short* __restrict__ Ahi_g, const unsigned short* __restrict__ Alo_g,
              const unsigned short* __restrict__ Bhi_g, const unsigned short* __restrict__ Blo_g,
              const float* __restrict__ bias0, const float* __restrict__ bias1,
              const float* __restrict__ bias2,
              float* __restrict__ C, int ldc,
              unsigned short* __restrict__ Vout)
{
  __shared__ __align__(16) unsigned short Ah[128*32];
  __shared__ __align__(16) unsigned short Bh[128*32];
  __shared__ __align__(16) unsigned short Al[COMP ? 128*32 : 8];
  __shared__ __align__(16) unsigned short Bl[COMP ? 128*32 : 8];

  const int tid = threadIdx.x, lane = tid & 63, wv = tid >> 6;
  const int wm = wv >> 1, wn = wv & 1;
  const int mi = lane & 15, quad = lane >> 4;

  // bijective XCD swizzle (nwg % 8 == 0 for both instantiations)
  int bid = blockIdx.y*gridDim.x + blockIdx.x;
  const int cpx = (gridDim.x*gridDim.y) >> 3;
  bid = (bid & 7)*cpx + (bid >> 3);
  const int n0 = (bid % gridDim.x) * 128;
  const int m0 = (bid / gridDim.x) * 128;

  const int seg = n0 >> 10;
  const float* bias = (seg == 0) ? bias0 : (seg == 1) ? bias1 : bias2;
  const int nw = n0 & 1023;
  const bool comp = COMP && (seg < 2);

  f32x4 acc[4][4];
  #pragma unroll
  for (int a = 0; a < 4; ++a)
    #pragma unroll
    for (int b = 0; b < 4; ++b)
      acc[a][b] = (f32x4){0.f, 0.f, 0.f, 0.f};

  for (int k0 = 0; k0 < 1024; k0 += 32){
    __syncthreads();
    #pragma unroll
    for (int t = 0; t < 2; ++t){
      int j = wv*128 + t*64 + lane;
      int row = j >> 2, c16 = j & 3;
      size_t ga = (size_t)(m0 + row)*1024 + k0 + c16*8;
      size_t gb = (size_t)(n0 + row)*1024 + k0 + c16*8;
      ld_g2l16(Ahi_g + ga, Ah + j*8);
      ld_g2l16(Bhi_g + gb, Bh + j*8);
      if (comp){
        ld_g2l16(Alo_g + ga, Al + j*8);
        ld_g2l16(Blo_g + gb, Bl + j*8);
      }
    }
    __syncthreads();

    bf16x8 ah[4], al[4];
    #pragma unroll
    for (int a = 0; a < 4; ++a){
      int r = wm*64 + a*16 + mi;
      ah[a] = __builtin_bit_cast(bf16x8, *(const short8*)(Ah + r*32 + quad*8));
      if (comp)
        al[a] = __builtin_bit_cast(bf16x8, *(const short8*)(Al + r*32 + quad*8));
    }
    #pragma unroll
    for (int b = 0; b < 4; ++b){
      int r = wn*64 + b*16 + mi;
      bf16x8 bh = __builtin_bit_cast(bf16x8, *(const short8*)(Bh + r*32 + quad*8));
      if (comp){
        bf16x8 bl = __builtin_bit_cast(bf16x8, *(const short8*)(Bl + r*32 + quad*8));
        #pragma unroll
        for (int a = 0; a < 4; ++a){
          acc[a][b] = __builtin_amdgcn_mfma_f32_16x16x32_bf16(al[a], bh, acc[a][b], 0, 0, 0);
          acc[a][b] = __builtin_amdgcn_mfma_f32_16x16x32_bf16(ah[a], bl, acc[a][b], 0, 0, 0);
          acc[a][b] = __builtin_amdgcn_mfma_f32_16x16x32_bf16(ah[a], bh, acc[a][b], 0, 0, 0);
        }
      } else {
        #pragma unroll
        for (int a = 0; a < 4; ++a)
          acc[a][b] = __builtin_amdgcn_mfma_f32_16x16x32_bf16(ah[a], bh, acc[a][b], 0, 0, 0);
      }
    }
  }

  if (COMP && seg == 2){
    // v: emit bf16 head-major directly (skips the P round-trip)
    #pragma unroll
    for (int a = 0; a < 4; ++a)
      #pragma unroll
      for (int b = 0; b < 4; ++b)
        #pragma unroll
        for (int r = 0; r < 4; ++r){
          int row = m0 + wm*64 + a*16 + quad*4 + r;
          int col = nw + wn*64 + b*16 + mi;
          int bb2 = row >> 11, t2 = row & 2047;
          Vout[(((size_t)(bb2*H_ + (col >> 6))*T_ + t2) << 6) + (col & 63)] =
              f2bf(acc[a][b][r] + bias[col]);
        }
  } else {
    #pragma unroll
    for (int a = 0; a < 4; ++a)
      #pragma unroll
      for (int b = 0; b < 4; ++b)
        #pragma unroll
        for (int r = 0; r < 4; ++r){
          int row  = m0 + wm*64 + a*16 + quad*4 + r;
          int coll = wn*64 + b*16 + mi;
          C[(size_t)row*ldc + n0 + coll] = acc[a][b][r] + bias[nw + coll];
        }
  }
}

// ---------------------------------------------------------------------------
// Normalize q,k rows of P; emit head-major bf16: Qhi/Qlo/Khi/Klo (v handled
// by the GEMM epilogue now).
// ---------------------------------------------------------------------------
__global__ __launch_bounds__(256)
void norm_split(const float* __restrict__ P,
                unsigned short* __restrict__ Qhi, unsigned short* __restrict__ Qlo,
                unsigned short* __restrict__ Khi, unsigned short* __restrict__ Klo)
{
  const int row = blockIdx.x, tid = threadIdx.x;
  const int bb = row >> 11, t = row & 2047;
  const int lane = tid & 63, wv = tid >> 6;
  const size_t base = (size_t)row * LDP;
  float4 q4 = *(const float4*)(P + base + tid*4);
  float4 k4 = *(const float4*)(P + base + 1024 + tid*4);
  float sq = wsum(q4.x*q4.x + q4.y*q4.y + q4.z*q4.z + q4.w*q4.w);
  float sk = wsum(k4.x*k4.x + k4.y*k4.y + k4.z*k4.z + k4.w*k4.w);
  __shared__ float rq[4], rk[4];
  if (lane == 0){ rq[wv] = sq; rk[wv] = sk; }
  __syncthreads();
  float cq = 1.f / fmaxf(sqrtf(rq[0]+rq[1]+rq[2]+rq[3]), 1e-12f);
  float ck = 1.f / fmaxf(sqrtf(rk[0]+rk[1]+rk[2]+rk[3]), 1e-12f);
  float qf[4] = {q4.x*cq, q4.y*cq, q4.z*cq, q4.w*cq};
  float kf[4] = {k4.x*ck, k4.y*ck, k4.z*ck, k4.w*ck};

  const int h = tid >> 4, d0 = (tid & 15)*4;
  const size_t ob = ((size_t)(bb*H_ + h)*T_ + t)*64 + d0;

  uint2 qh, ql, kh, kl;
  unsigned short t0,t1,t2,t3;
  t0=f2bf(qf[0]); t1=f2bf(qf[1]); t2=f2bf(qf[2]); t3=f2bf(qf[3]);
  qh.x = t0 | ((unsigned)t1<<16); qh.y = t2 | ((unsigned)t3<<16);
  ql.x = f2bf(qf[0]-bf2f(t0)) | ((unsigned)f2bf(qf[1]-bf2f(t1))<<16);
  ql.y = f2bf(qf[2]-bf2f(t2)) | ((unsigned)f2bf(qf[3]-bf2f(t3))<<16);
  t0=f2bf(kf[0]); t1=f2bf(kf[1]); t2=f2bf(kf[2]); t3=f2bf(kf[3]);
  kh.x = t0 | ((unsigned)t1<<16); kh.y = t2 | ((unsigned)t3<<16);
  kl.x = f2bf(kf[0]-bf2f(t0)) | ((unsigned)f2bf(kf[1]-bf2f(t1))<<16);
  kl.y = f2bf(kf[2]-bf2f(t2)) | ((unsigned)f2bf(kf[3]-bf2f(t3))<<16);
  *(uint2*)(Qhi + ob) = qh;  *(uint2*)(Qlo + ob) = ql;
  *(uint2*)(Khi + ob) = kh;  *(uint2*)(Klo + ob) = kl;
}

// ---------------------------------------------------------------------------
// Staging helpers for the pipelined attn: global->reg issue, reg->LDS write.
// ---------------------------------------------------------------------------
__device__ __forceinline__ void stage_issue(
    const unsigned short* __restrict__ Khi_g, const unsigned short* __restrict__ Klo_g,
    const unsigned short* __restrict__ Vbf, size_t hb, int jt, int tid,
    uint2* khr, uint2* klr, ushort4* vra, ushort4* vrb)
{
  #pragma unroll
  for (int i = 0; i < 4; ++i){
    int idx = tid + i*256;
    int row = idx >> 4, c4 = idx & 15;
    size_t g = (hb + jt*64 + row)*64 + c4*4;
    khr[i] = *(const uint2*)(Khi_g + g);
    klr[i] = *(const uint2*)(Klo_g + g);
  }
  #pragma unroll
  for (int i = 0; i < 2; ++i){
    int idx = tid + i*256;
    int rp = idx & 31, d4 = idx >> 5;
    size_t g = (hb + jt*64 + 2*rp)*64 + d4*4;
    vra[i] = *(const ushort4*)(Vbf + g);
    vrb[i] = *(const ushort4*)(Vbf + g + 64);
  }
}

__device__ __forceinline__ void stage_write(char* bufc, int tid,
    const uint2* khr, const uint2* klr, const ushort4* vra, const ushort4* vrb)
{
  unsigned short* Kh = (unsigned short*)bufc;
  unsigned short* Kl = (unsigned short*)(bufc + 9216);
  unsigned* vt = (unsigned*)(bufc + 18432);
  #pragma unroll
  for (int i = 0; i < 4; ++i){
    int idx = tid + i*256;
    int row = idx >> 4, c4 = idx & 15;
    *(uint2*)(Kh + row*ST + c4*4) = khr[i];
    *(uint2*)(Kl + row*ST + c4*4) = klr[i];
  }
  #pragma unroll
  for (int i = 0; i < 2; ++i){
    int idx = tid + i*256;
    int rp = idx & 31, d4 = idx >> 5;
    vt[(d4*4+0)*36 + rp] = (unsigned)vra[i].x | ((unsigned)vrb[i].x << 16);
    vt[(d4*4+1)*36 + rp] = (unsigned)vra[i].y | ((unsigned)vrb[i].y << 16);
    vt[(d4*4+2)*36 + rp] = (unsigned)vra[i].z | ((unsigned)vrb[i].z << 16);
    vt[(d4*4+3)*36 + rp] = (unsigned)vra[i].w | ((unsigned)vrb[i].w << 16);
  }
}

// ---------------------------------------------------------------------------
// One q-tile's score + online-softmax + PV update against the staged K/V tile.
// ---------------------------------------------------------------------------
__device__ __forceinline__ void attn_tile(
    const unsigned short* __restrict__ Kh, const unsigned short* __restrict__ Kl,
    const unsigned short* __restrict__ Vt, unsigned short* __restrict__ pw,
    const bf16x8* qh, const bf16x8* ql,
    f32x4* O, float& mr, float& lr,
    bool last, int relrow, int mi, int quad)
{
  f32x4 st[4];
  #pragma unroll
  for (int mt = 0; mt < 4; ++mt) st[mt] = (f32x4){0.f,0.f,0.f,0.f};
  __builtin_amdgcn_s_setprio(1);
  #pragma unroll
  for (int mt = 0; mt < 4; ++mt){
    int krow = mt*16 + mi;
    #pragma unroll
    for (int ks = 0; ks < 2; ++ks){
      bf16x8 kh = __builtin_bit_cast(bf16x8, *(const short8*)(Kh + krow*ST + ks*32 + quad*8));
      bf16x8 kl = __builtin_bit_cast(bf16x8, *(const short8*)(Kl + krow*ST + ks*32 + quad*8));
      st[mt] = __builtin_amdgcn_mfma_f32_16x16x32_bf16(kl, qh[ks], st[mt], 0, 0, 0);
      st[mt] = __builtin_amdgcn_mfma_f32_16x16x32_bf16(kh, ql[ks], st[mt], 0, 0, 0);
      st[mt] = __builtin_amdgcn_mfma_f32_16x16x32_bf16(kh, qh[ks], st[mt], 0, 0, 0);
    }
  }
  __builtin_amdgcn_s_setprio(0);

  float tmax = -INFINITY;
  #pragma unroll
  for (int mt = 0; mt < 4; ++mt)
    #pragma unroll
    for (int r = 0; r < 4; ++r){
      float s = st[mt][r] * SCALE_F;
      if (last){
        int key = mt*16 + quad*4 + r;
        if (key > relrow) s = -INFINITY;
      }
      st[mt][r] = s;
      tmax = fmaxf(tmax, s);
    }
  tmax = fmaxf(tmax, __shfl_xor(tmax, 16));
  tmax = fmaxf(tmax, __shfl_xor(tmax, 32));
  float mnew = fmaxf(mr, tmax);
  float alpha = __expf(mr - mnew);
  mr = mnew;
  float tsum = 0.f;
  #pragma unroll
  for (int mt = 0; mt < 4; ++mt)
    #pragma unroll
    for (int r = 0; r < 4; ++r){
      float p = __expf(st[mt][r] - mnew);
      st[mt][r] = p;
      tsum += p;
    }
  tsum += __shfl_xor(tsum, 16);
  tsum += __shfl_xor(tsum, 32);
  lr = lr*alpha + tsum;

  #pragma unroll
  for (int mt = 0; mt < 4; ++mt){
    uint2 pk;
    pk.x = (unsigned)f2bf(st[mt][0]) | ((unsigned)f2bf(st[mt][1]) << 16);
    pk.y = (unsigned)f2bf(st[mt][2]) | ((unsigned)f2bf(st[mt][3]) << 16);
    *(uint2*)(pw + mi*ST + mt*16 + quad*4) = pk;
  }

  float af[4];
  #pragma unroll
  for (int r = 0; r < 4; ++r) af[r] = __shfl(alpha, quad*4 + r);
  #pragma unroll
  for (int dn = 0; dn < 4; ++dn)
    #pragma unroll
    for (int r = 0; r < 4; ++r) O[dn][r] *= af[r];

  __builtin_amdgcn_s_setprio(1);
  #pragma unroll
  for (int kt = 0; kt < 2; ++kt){
    bf16x8 pf = __builtin_bit_cast(bf16x8, *(const short8*)(pw + mi*ST + kt*32 + quad*8));
    #pragma unroll
    for (int dn = 0; dn < 4; ++dn){
      bf16x8 vf = __builtin_bit_cast(bf16x8, *(const short8*)(Vt + (dn*16 + mi)*ST + kt*32 + quad*8));
      O[dn] = __builtin_amdgcn_mfma_f32_16x16x32_bf16(pf, vf, O[dn], 0, 0, 0);
    }
  }
  __builtin_amdgcn_s_setprio(0);
}

// ---------------------------------------------------------------------------
// Paired-tile flash attention + parallel KNN + gate, double-buffered K/V LDS
// with async-stage split (T14). Grid 512 (1D), XCD-grouped: each XCD owns 4
// complete (b,h) groups so the 16 pair-blocks sharing a K/V stream hit the
// same L2. id = xcd + 8*slot (dispatch round-robin) -> g = (slot>>4)*8+xcd.
// ---------------------------------------------------------------------------
__global__ __launch_bounds__(256)
void attn_knn(const unsigned short* __restrict__ Qhi, const unsigned short* __restrict__ Qlo,
              const unsigned short* __restrict__ Khi_g, const unsigned short* __restrict__ Klo_g,
              const unsigned short* __restrict__ Vbf,
              const float* __restrict__ mem_bank, const int* __restrict__ knn_idx,
              const float* __restrict__ gate_bias, unsigned short* __restrict__ comb)
{
  __shared__ __align__(16) char smpool[64512];
  float* qkvs = (float*)smpool;                            // overlay 128 x 68 fp32 (epilogue)

  const int id = blockIdx.x;           // 0..511
  const int xcd = id & 7, slot = id >> 3;
  const int g_ = (slot >> 4)*8 + xcd;  // (b,h) group 0..31
  const int bb = g_ >> 4, h = g_ & 15;
  const int p = slot & 15;             // pair id 0..15
  const int jA = p, jB = 31 - p;
  const int tid = threadIdx.x, lane = tid & 63, wv = tid >> 6;
  const int mi = lane & 15, quad = lane >> 4;
  const int relrow = wv*16 + mi;
  const size_t hb = (size_t)(bb*H_ + h)*T_;
  unsigned short* pw = (unsigned short*)(smpool + 55296) + wv*1152;

  // KNN epilogue geometry + idx prefetch
  const int sub = lane & 3;
  const int grp = tid >> 2;          // 0..63 (row within tile)
  const int base = lane & 60;        // group base lane within wave
  int idxP[2];
  idxP[0] = (sub < 3) ? knn_idx[((size_t)bb*T_ + jA*64 + grp)*3 + sub] : 0;
  idxP[1] = (sub < 3) ? knn_idx[((size_t)bb*T_ + jB*64 + grp)*3 + sub] : 0;

  bf16x8 qhA[2], qlA[2], qhB[2], qlB[2];
  #pragma unroll
  for (int ks = 0; ks < 2; ++ks){
    qhA[ks] = __builtin_bit_cast(bf16x8, *(const uint4*)(Qhi + (hb + jA*64 + relrow)*64 + ks*32 + quad*8));
    qlA[ks] = __builtin_bit_cast(bf16x8, *(const uint4*)(Qlo + (hb + jA*64 + relrow)*64 + ks*32 + quad*8));
    qhB[ks] = __builtin_bit_cast(bf16x8, *(const uint4*)(Qhi + (hb + jB*64 + relrow)*64 + ks*32 + quad*8));
    qlB[ks] = __builtin_bit_cast(bf16x8, *(const uint4*)(Qlo + (hb + jB*64 + relrow)*64 + ks*32 + quad*8));
  }

  f32x4 OA[4], OB[4];
  #pragma unroll
  for (int dn = 0; dn < 4; ++dn){
    OA[dn] = (f32x4){0.f,0.f,0.f,0.f};
    OB[dn] = (f32x4){0.f,0.f,0.f,0.f};
  }
  float mA = -INFINITY, lA = 0.f, mB = -INFINITY, lB = 0.f;

  const int ntiles = jB + 1;           // >= 17 always

  // --- pipelined staging: prologue ---
  uint2 khr[4], klr[4]; ushort4 vra[2], vrb[2];
  stage_issue(Khi_g, Klo_g, Vbf, hb, 0, tid, khr, klr, vra, vrb);
  stage_write(smpool, tid, khr, klr, vra, vrb);
  stage_issue(Khi_g, Klo_g, Vbf, hb, 1, tid, khr, klr, vra, vrb);

  int cur = 0;
  for (int jt = 0; jt < ntiles; ++jt){
    __syncthreads();                    // buf[cur] writes visible; buf[cur^1] free
    if (jt + 1 < ntiles){
      stage_write(smpool + (cur^1)*27648, tid, khr, klr, vra, vrb);
      if (jt + 2 < ntiles)
        stage_issue(Khi_g, Klo_g, Vbf, hb, jt+2, tid, khr, klr, vra, vrb);
    }
    char* bufc = smpool + cur*27648;
    const unsigned short* Kh = (const unsigned short*)bufc;
    const unsigned short* Kl = (const unsigned short*)(bufc + 9216);
    const unsigned short* Vt = (const unsigned short*)(bufc + 18432);
    if (jt <= jA)
      attn_tile(Kh, Kl, Vt, pw, qhA, qlA, OA, mA, lA, jt == jA, relrow, mi, quad);
    attn_tile(Kh, Kl, Vt, pw, qhB, qlB, OB, mB, lB, jt == jB, relrow, mi, quad);
    cur ^= 1;
  }

  __syncthreads();
  {
    float liA[4], liB[4];
    #pragma unroll
    for (int r = 0; r < 4; ++r){
      liA[r] = 1.f / __shfl(lA, quad*4 + r);
      liB[r] = 1.f / __shfl(lB, quad*4 + r);
    }
    #pragma unroll
    for (int dn = 0; dn < 4; ++dn)
      #pragma unroll
      for (int r = 0; r < 4; ++r){
        qkvs[(      wv*16 + quad*4 + r)*68 + dn*16 + mi] = OA[dn][r] * liA[r];
        qkvs[(64 +  wv*16 + quad*4 + r)*68 + dn*16 + mi] = OB[dn][r] * liB[r];
      }
  }
  __syncthreads();

  // ---- parallel KNN + gate: 4-lane group per row, 16 dims per lane ----
  const float g = gate_bias[h];
  const float gq = 1.f - g;

  #pragma unroll
  for (int it = 0; it < 2; ++it){
    const int jq = it ? jB : jA;
    const int trow = jq*64 + grp;
    const int lrow = it*64 + grp;

    int idxs[3];
    #pragma unroll
    for (int kk = 0; kk < 3; ++kk) idxs[kk] = __shfl(idxP[it], base + kk);

    // issue ALL gather loads upfront (mk + mv are independent of the softmax)
    float4 mk4[3][4], mv4[3][4];
    #pragma unroll
    for (int kk = 0; kk < 3; ++kk){
      const float* mk = mem_bank + (((size_t)bb*M_ + idxs[kk])*2 + 0)*D_ + h*HD_ + sub*16;
      const float* mv = mem_bank + (((size_t)bb*M_ + idxs[kk])*2 + 1)*D_ + h*HD_ + sub*16;
      #pragma unroll
      for (int j4 = 0; j4 < 4; ++j4){
        mk4[kk][j4] = *(const float4*)(mk + j4*4);
        mv4[kk][j4] = *(const float4*)(mv + j4*4);
      }
    }

    float qf[16];
    {
      const unsigned short* qp = Qhi + (hb + trow)*64 + sub*16;
      const unsigned short* lp = Qlo + (hb + trow)*64 + sub*16;
      unsigned short hs[16], ls[16];
      *(uint4*)hs     = *(const uint4*)qp;
      *(uint4*)(hs+8) = *(const uint4*)(qp+8);
      *(uint4*)ls     = *(const uint4*)lp;
      *(uint4*)(ls+8) = *(const uint4*)(lp+8);
      #pragma unroll
      for (int j = 0; j < 16; ++j) qf[j] = bf2f(hs[j]) + bf2f(ls[j]);
    }

    float dts[3]; float mx = -INFINITY;
    #pragma unroll
    for (int kk = 0; kk < 3; ++kk){
      float dsum = 0.f;
      #pragma unroll
      for (int j4 = 0; j4 < 4; ++j4){
        float4 m4 = mk4[kk][j4];
        dsum += qf[j4*4+0]*m4.x + qf[j4*4+1]*m4.y + qf[j4*4+2]*m4.z + qf[j4*4+3]*m4.w;
      }
      dsum += __shfl_xor(dsum, 1);
      dsum += __shfl_xor(dsum, 2);
      dsum *= SCALE_F;
      dts[kk] = dsum;
      mx = fmaxf(mx, dsum);
    }
    float e0 = __expf(dts[0]-mx), e1 = __expf(dts[1]-mx), e2 = __expf(dts[2]-mx);
    float inv = 1.f/(e0+e1+e2);
    float w[3] = {e0*inv, e1*inv, e2*inv};

    float ov[16];
    #pragma unroll
    for (int j = 0; j < 16; ++j) ov[j] = 0.f;
    #pragma unroll
    for (int kk = 0; kk < 3; ++kk){
      #pragma unroll
      for (int j4 = 0; j4 < 4; ++j4){
        float4 m4 = mv4[kk][j4];
        ov[j4*4+0] += w[kk]*m4.x;
        ov[j4*4+1] += w[kk]*m4.y;
        ov[j4*4+2] += w[kk]*m4.z;
        ov[j4*4+3] += w[kk]*m4.w;
      }
    }

    unsigned short os[16];
    #pragma unroll
    for (int j = 0; j < 16; ++j){
      float qkv = qkvs[lrow*68 + sub*16 + j];
      os[j] = f2bf(ov[j]*g + qkv*gq);
    }
    unsigned short* op = comb + ((size_t)bb*T_ + trow)*D_ + h*HD_ + sub*16;
    *(uint4*)op     = *(uint4*)os;
    *(uint4*)(op+8) = *(uint4*)(os+8);
  }
}

extern "C" void kernel_launch(void* const* d_in, const int* in_sizes, int n_in,
                              void* d_out, int out_size, void* d_ws, size_t ws_size,
                              hipStream_t stream)
{
  (void)in_sizes; (void)n_in; (void)out_size; (void)ws_size;
  const float* x    = (const float*)d_in[0];
  const float* Wq   = (const float*)d_in[1];
  const float* bq   = (const float*)d_in[2];
  const float* Wk   = (const float*)d_in[3];
  const float* bk   = (const float*)d_in[4];
  const float* Wv   = (const float*)d_in[5];
  const float* bv   = (const float*)d_in[6];
  const float* Wo   = (const float*)d_in[7];
  const float* bo   = (const float*)d_in[8];
  const float* gate = (const float*)d_in[9];
  const float* mem  = (const float*)d_in[10];
  const int*   knn  = (const int*)d_in[11];

  char* ws = (char*)d_ws;
  float*          P    = (float*)ws;                               // 48 MB
  unsigned short* comb = (unsigned short*)ws;                      // 8 MB, aliases P
  unsigned short* Qhi  = (unsigned short*)(ws +  50331648);
  unsigned short* Qlo  = (unsigned short*)(ws +  58720256);
  unsigned short* Khi  = (unsigned short*)(ws +  67108864);
  unsigned short* Klo  = (unsigned short*)(ws +  75497472);
  unsigned short* Vbf  = (unsigned short*)(ws +  83886080);
  unsigned short* Xhi  = (unsigned short*)(ws +  92274688);
  unsigned short* Xlo  = (unsigned short*)(ws + 100663296);
  unsigned short* Whi  = (unsigned short*)(ws + 109051904);        // 3072x1024
  unsigned short* Wlo  = (unsigned short*)(ws + 115343360);        // 2048x1024 (q,k only)
  unsigned short* Wohi = (unsigned short*)(ws + 119537664);        // 1024x1024

  cvt_all<<<8192, 256, 0, stream>>>(x, Wq, Wk, Wv, Wo, Xhi, Xlo, Whi, Wlo, Wohi);
  gemm_lds<true><<<dim3(24, 32), 256, 0, stream>>>(Xhi, Xlo, Whi, Wlo, bq, bk, bv, P, LDP, Vbf);
  norm_split<<<4096, 256, 0, stream>>>(P, Qhi, Qlo, Khi, Klo);
  attn_knn<<<512, 256, 0, stream>>>(Qhi, Qlo, Khi, Klo, Vbf, mem, knn, gate, comb);
  gemm_lds<false><<<dim3(8, 32), 256, 0, stream>>>(comb, nullptr, Wohi, nullptr,
                                                   bo, bo, bo, (float*)d_out, D_, nullptr);
}